// Round 1
// baseline (432.670 us; speedup 1.0000x reference)
//
#include <hip/hip_runtime.h>
#include <hip/hip_bf16.h>
#include <math.h>

#define Bb 16
#define Ll 256
#define Hh 6
#define Dm 768
#define dh 128

// ws offsets (in floats)
#define OFF_X    0UL
#define OFF_VC   3145728UL
#define OFF_CO   6291456UL
#define OFF_SQ   12582912UL
#define OFF_THS  12607488UL
#define OFF_PART 12632064UL
#define OFF_STAT 12632832UL
#define OFF_ACC  12632896UL

// ---------------- K1: gather + scale, per-(token,head) sum / sumsq ----------------
__global__ __launch_bounds__(128) void k1_gather(const int* __restrict__ tids,
    const float* __restrict__ TF, const float* __restrict__ DF,
    const float* __restrict__ emb, float* __restrict__ x,
    float* __restrict__ sq, float* __restrict__ ths) {
  int tok = blockIdx.x;            // b*L + l
  int t = threadIdx.x;             // 0..127
  int tid = tids[tok];
  float w = fminf(TF[tok], 20.0f) * log1pf(1.0f / DF[tok]);
  const float* er = emb + (size_t)tid * Dm;
  float* xr = x + (size_t)tok * Dm;
  float v[6];
#pragma unroll
  for (int k = 0; k < 6; ++k) {
    float e = er[t + 128 * k] * w;
    xr[t + 128 * k] = e;
    v[k] = e;
  }
  __shared__ float s1[6][2], s2[6][2];
  int lane = t & 63, wid = t >> 6;
#pragma unroll
  for (int k = 0; k < 6; ++k) {
    float a = v[k], q = v[k] * v[k];
#pragma unroll
    for (int off = 32; off >= 1; off >>= 1) {
      a += __shfl_down(a, off);
      q += __shfl_down(q, off);
    }
    if (lane == 0) { s1[k][wid] = a; s2[k][wid] = q; }
  }
  __syncthreads();
  if (t < 6) {
    int bb = tok >> 8, l = tok & 255;
    size_t idx = ((size_t)(bb * 6 + t)) * 256 + l;
    ths[idx] = s1[t][0] + s1[t][1];
    sq[idx]  = s2[t][0] + s2[t][1];
  }
}

// ---------------- K2: distance matrix per (b,h): 128x128 tile X.X^T ----------------
__global__ __launch_bounds__(256) void k2_dist(const float* __restrict__ x,
    const float* __restrict__ sq, float* __restrict__ co, float* __restrict__ part) {
  int tile = blockIdx.x;       // 0..3
  int bh = blockIdx.y;         // b*6+h
  int b = bh / 6, h = bh % 6;
  int I = (tile >> 1) * 128, J = (tile & 1) * 128;
  __shared__ float Xi[128][36];   // pad 36: float4-aligned rows, conflict-free reads
  __shared__ float Xj[128][36];
  int tid = threadIdx.x;
  int tr = tid >> 4, tc = tid & 15;
  float acc[8][8];
#pragma unroll
  for (int a = 0; a < 8; ++a)
#pragma unroll
    for (int q = 0; q < 8; ++q) acc[a][q] = 0.0f;
  const float* xb = x + (size_t)b * Ll * Dm + h * dh;
  for (int kc = 0; kc < 4; ++kc) {
    int r0 = tid >> 3, c4 = (tid & 7) * 4;
#pragma unroll
    for (int p = 0; p < 4; ++p) {
      int r = r0 + 32 * p;
      float4 vi = *(const float4*)(xb + (size_t)(I + r) * Dm + kc * 32 + c4);
      float4 vj = *(const float4*)(xb + (size_t)(J + r) * Dm + kc * 32 + c4);
      *(float4*)&Xi[r][c4] = vi;
      *(float4*)&Xj[r][c4] = vj;
    }
    __syncthreads();
#pragma unroll
    for (int k0 = 0; k0 < 32; k0 += 4) {
      float4 af[8], bf[8];
#pragma unroll
      for (int a = 0; a < 8; ++a) af[a] = *(const float4*)&Xi[tr + 16 * a][k0];
#pragma unroll
      for (int q = 0; q < 8; ++q) bf[q] = *(const float4*)&Xj[tc + 16 * q][k0];
#pragma unroll
      for (int a = 0; a < 8; ++a)
#pragma unroll
        for (int q = 0; q < 8; ++q)
          acc[a][q] += af[a].x * bf[q].x + af[a].y * bf[q].y
                     + af[a].z * bf[q].z + af[a].w * bf[q].w;
    }
    __syncthreads();
  }
  const float* sqh = sq + (size_t)bh * 256;
  float si[8], sj[8];
#pragma unroll
  for (int a = 0; a < 8; ++a) si[a] = sqh[I + tr + 16 * a];
#pragma unroll
  for (int q = 0; q < 8; ++q) sj[q] = sqh[J + tc + 16 * q];
  float ls1 = 0.0f, ls2 = 0.0f;
  float* cob = co + (size_t)bh * 256 * 256;
#pragma unroll
  for (int a = 0; a < 8; ++a) {
#pragma unroll
    for (int q = 0; q < 8; ++q) {
      float g = acc[a][q];
      float d2 = si[a] + sj[q] - 2.0f * g;
      float cv = sqrtf(fmaxf(d2, 1e-12f));
      cob[(size_t)(I + tr + 16 * a) * 256 + (J + tc + 16 * q)] = cv;
      ls1 += cv; ls2 += cv * cv;
    }
  }
#pragma unroll
  for (int off = 32; off >= 1; off >>= 1) {
    ls1 += __shfl_down(ls1, off);
    ls2 += __shfl_down(ls2, off);
  }
  __shared__ float rs[2][4];
  int lane = tid & 63, wid = tid >> 6;
  if (lane == 0) { rs[0][wid] = ls1; rs[1][wid] = ls2; }
  __syncthreads();
  if (tid == 0) {
    part[((size_t)bh * 4 + tile) * 2 + 0] = rs[0][0] + rs[0][1] + rs[0][2] + rs[0][3];
    part[((size_t)bh * 4 + tile) * 2 + 1] = rs[1][0] + rs[1][1] + rs[1][2] + rs[1][3];
  }
}

// ---------------- K3: finalize BN stats, zero logit accumulator ----------------
__global__ __launch_bounds__(384) void k3_stats(const float* __restrict__ ths,
    const float* __restrict__ sq, const float* __restrict__ part,
    float* __restrict__ stats, float* __restrict__ acc) {
  int h = threadIdx.x >> 6, lane = threadIdx.x & 63;
  float s1 = 0.0f, s2 = 0.0f;
  for (int m = 0; m < 64; ++m) {
    int f = m * 64 + lane;               // 0..4095 token id
    int bb = f >> 8, l = f & 255;
    size_t idx = ((size_t)(bb * 6 + h)) * 256 + l;
    s1 += ths[idx]; s2 += sq[idx];
  }
#pragma unroll
  for (int off = 32; off >= 1; off >>= 1) {
    s1 += __shfl_down(s1, off);
    s2 += __shfl_down(s2, off);
  }
  if (lane == 0) {
    float cnt = 524288.0f;               // B*L*dh
    float mean = s1 / cnt;
    float var = s2 / cnt - mean * mean;
    stats[h] = mean;
    stats[6 + h] = rsqrtf(var + 1e-5f);
  }
  int bb = lane >> 2, t = lane & 3;
  size_t pidx = ((size_t)(bb * 6 + h) * 4 + t) * 2;
  float c1 = part[pidx], c2 = part[pidx + 1];
#pragma unroll
  for (int off = 32; off >= 1; off >>= 1) {
    c1 += __shfl_down(c1, off);
    c2 += __shfl_down(c2, off);
  }
  if (lane == 0) {
    float cnt = 1048576.0f;              // B*L*L
    float mean = c1 / cnt;
    float var = c2 / cnt - mean * mean;
    stats[12 + h] = mean;
    stats[18 + h] = rsqrtf(var + 1e-5f);
  }
  if (threadIdx.x < 336) acc[threadIdx.x] = 0.0f;
}

// ---------------- K4: bn + leaky9 + mask + row softmax (wave per row) ----------------
__global__ __launch_bounds__(256) void k4_softmax(float* __restrict__ co,
    const int* __restrict__ tids, const float* __restrict__ stats) {
  int row = blockIdx.x * 4 + (threadIdx.x >> 6);   // bh*256 + i
  int lane = threadIdx.x & 63;
  int bh = row >> 8, i = row & 255;
  int b = bh / 6, h = bh % 6;
  float m = stats[12 + h], r = stats[18 + h];
  float* cr = co + (size_t)row * 256;
  float4 v = *(float4*)(cr + lane * 4);
  float t0 = (v.x - m) * r, t1 = (v.y - m) * r, t2 = (v.z - m) * r, t3 = (v.w - m) * r;
  t0 = t0 >= 0.0f ? t0 : 9.0f * t0;
  t1 = t1 >= 0.0f ? t1 : 9.0f * t1;
  t2 = t2 >= 0.0f ? t2 : 9.0f * t2;
  t3 = t3 >= 0.0f ? t3 : 9.0f * t3;
  const int* tb = tids + b * 256;
  int vi = (tb[i] != 0);
  int4 tj = *(const int4*)(tb + lane * 4);
  if (!vi || tj.x == 0) t0 = 0.0f;
  if (!vi || tj.y == 0) t1 = 0.0f;
  if (!vi || tj.z == 0) t2 = 0.0f;
  if (!vi || tj.w == 0) t3 = 0.0f;
  float mx = fmaxf(fmaxf(t0, t1), fmaxf(t2, t3));
#pragma unroll
  for (int off = 32; off >= 1; off >>= 1) mx = fmaxf(mx, __shfl_xor(mx, off));
  float e0 = expf(t0 - mx), e1 = expf(t1 - mx), e2 = expf(t2 - mx), e3 = expf(t3 - mx);
  float s = e0 + e1 + e2 + e3;
#pragma unroll
  for (int off = 32; off >= 1; off >>= 1) s += __shfl_xor(s, off);
  float inv = 1.0f / s;
  v.x = e0 * inv; v.y = e1 * inv; v.z = e2 * inv; v.w = e3 * inv;
  *(float4*)(cr + lane * 4) = v;
}

// ---------------- K5a: V_out = co_soft @ Vn, write Vc in (B,L,D) ----------------
__global__ __launch_bounds__(256) void k5a_vout(const float* __restrict__ co,
    const float* __restrict__ x, const float* __restrict__ stats,
    float* __restrict__ vc) {
  int I = blockIdx.x * 64;
  int bh = blockIdx.y;
  int b = bh / 6, h = bh % 6;
  __shared__ float cs[64][68];
  __shared__ float vs[64][128];
  int tid = threadIdx.x;
  int tx = tid & 31, ty = tid >> 5;
  float vnm = stats[h], vnr = stats[6 + h];
  float4 acc[8];
#pragma unroll
  for (int s = 0; s < 8; ++s) acc[s] = make_float4(0.f, 0.f, 0.f, 0.f);
  const float* cob = co + ((size_t)bh * 256 + I) * 256;
  const float* xb = x + (size_t)b * Ll * Dm + h * dh;
  for (int Jc = 0; Jc < 256; Jc += 64) {
    {
      int c4 = (tid & 15) * 4, r0 = tid >> 4;
#pragma unroll
      for (int p = 0; p < 4; ++p) {
        int rr = r0 + 16 * p;
        *(float4*)&cs[rr][c4] = *(const float4*)(cob + (size_t)rr * 256 + Jc + c4);
      }
    }
    {
      int c4 = (tid & 31) * 4, r0 = tid >> 5;
#pragma unroll
      for (int p = 0; p < 8; ++p) {
        int j = r0 + 8 * p;
        float4 e = *(const float4*)(xb + (size_t)(Jc + j) * Dm + c4);
        e.x = (e.x - vnm) * vnr; e.y = (e.y - vnm) * vnr;
        e.z = (e.z - vnm) * vnr; e.w = (e.w - vnm) * vnr;
        *(float4*)&vs[j][c4] = e;
      }
    }
    __syncthreads();
#pragma unroll
    for (int j0 = 0; j0 < 64; j0 += 4) {
      float4 vn0 = *(float4*)&vs[j0 + 0][tx * 4];
      float4 vn1 = *(float4*)&vs[j0 + 1][tx * 4];
      float4 vn2 = *(float4*)&vs[j0 + 2][tx * 4];
      float4 vn3 = *(float4*)&vs[j0 + 3][tx * 4];
#pragma unroll
      for (int s = 0; s < 8; ++s) {
        float4 c4v = *(float4*)&cs[ty + 8 * s][j0];
        acc[s].x += c4v.x * vn0.x + c4v.y * vn1.x + c4v.z * vn2.x + c4v.w * vn3.x;
        acc[s].y += c4v.x * vn0.y + c4v.y * vn1.y + c4v.z * vn2.y + c4v.w * vn3.y;
        acc[s].z += c4v.x * vn0.z + c4v.y * vn1.z + c4v.z * vn2.z + c4v.w * vn3.z;
        acc[s].w += c4v.x * vn0.w + c4v.y * vn1.w + c4v.z * vn2.w + c4v.w * vn3.w;
      }
    }
    __syncthreads();
  }
  float* vcb = vc + ((size_t)b * Ll + I) * Dm + h * dh;
#pragma unroll
  for (int s = 0; s < 8; ++s)
    *(float4*)(vcb + (size_t)(ty + 8 * s) * Dm + tx * 4) = acc[s];
}

// ---------------- K5b: V_lgts = softmax(Vc@fcW^T + fcb); accumulate per (b,c) ----------------
__global__ __launch_bounds__(256) void k5b_lgts(const float* __restrict__ vc,
    const float* __restrict__ fcW, const float* __restrict__ fcb,
    float* __restrict__ acc) {
  int wid = threadIdx.x >> 6, lane = threadIdx.x & 63;
  int token = blockIdx.x * 4 + wid;
  int b = token >> 8;
  const float* vr = vc + (size_t)token * Dm;
  float part[21];
#pragma unroll
  for (int c = 0; c < 21; ++c) part[c] = 0.0f;
  for (int m = 0; m < 12; ++m) {
    float v = vr[lane + 64 * m];
#pragma unroll
    for (int c = 0; c < 21; ++c)
      part[c] += v * fcW[c * 768 + lane + 64 * m];
  }
#pragma unroll
  for (int c = 0; c < 21; ++c) {
#pragma unroll
    for (int off = 32; off >= 1; off >>= 1)
      part[c] += __shfl_down(part[c], off);
  }
  __shared__ float sp[4][21];
  if (lane == 0) {
    float mx = -1e30f;
#pragma unroll
    for (int c = 0; c < 21; ++c) { part[c] += fcb[c]; mx = fmaxf(mx, part[c]); }
    float s = 0.0f;
#pragma unroll
    for (int c = 0; c < 21; ++c) { part[c] = expf(part[c] - mx); s += part[c]; }
    float inv = 1.0f / s;
#pragma unroll
    for (int c = 0; c < 21; ++c) sp[wid][c] = part[c] * inv;
  }
  __syncthreads();
  if (threadIdx.x < 21) {
    float s = sp[0][threadIdx.x] + sp[1][threadIdx.x] + sp[2][threadIdx.x] + sp[3][threadIdx.x];
    atomicAdd(&acc[b * 21 + threadIdx.x], s);
  }
}

// ---------------- K6: final softmax over first 20 classes ----------------
__global__ __launch_bounds__(64) void k6_final(const float* __restrict__ acc,
                                               float* __restrict__ out) {
  int b = threadIdx.x;
  if (b < 16) {
    float mx = -1e30f;
    for (int c = 0; c < 20; ++c) mx = fmaxf(mx, acc[b * 21 + c]);
    float e[20], s = 0.0f;
    for (int c = 0; c < 20; ++c) { e[c] = expf(acc[b * 21 + c] - mx); s += e[c]; }
    float inv = 1.0f / s;
    for (int c = 0; c < 20; ++c) out[b * 20 + c] = e[c] * inv;
  }
}

extern "C" void kernel_launch(void* const* d_in, const int* in_sizes, int n_in,
                              void* d_out, int out_size, void* d_ws, size_t ws_size,
                              hipStream_t stream) {
  const int*   tids = (const int*)d_in[0];
  const float* TF   = (const float*)d_in[1];
  const float* DF   = (const float*)d_in[2];
  const float* emb  = (const float*)d_in[3];
  const float* fcW  = (const float*)d_in[4];
  const float* fcb  = (const float*)d_in[5];
  // d_in[6]=weiW, d_in[7]=weib: dead code (cw branch is provably all-ones)
  float* out = (float*)d_out;
  float* ws  = (float*)d_ws;
  float* x     = ws + OFF_X;
  float* vc    = ws + OFF_VC;
  float* co    = ws + OFF_CO;
  float* sq    = ws + OFF_SQ;
  float* ths   = ws + OFF_THS;
  float* part  = ws + OFF_PART;
  float* stats = ws + OFF_STAT;
  float* acc   = ws + OFF_ACC;

  k1_gather<<<4096, 128, 0, stream>>>(tids, TF, DF, emb, x, sq, ths);
  k2_dist<<<dim3(4, 96), 256, 0, stream>>>(x, sq, co, part);
  k3_stats<<<1, 384, 0, stream>>>(ths, sq, part, stats, acc);
  k4_softmax<<<6144, 256, 0, stream>>>(co, tids, stats);
  k5a_vout<<<dim3(4, 96), 256, 0, stream>>>(co, x, stats, vc);
  k5b_lgts<<<1024, 256, 0, stream>>>(vc, fcW, fcb, acc);
  k6_final<<<1, 64, 0, stream>>>(acc, out);
}

// Round 2
// 276.226 us; speedup vs baseline: 1.5664x; 1.5664x over previous
//
#include <hip/hip_runtime.h>
#include <hip/hip_bf16.h>
#include <math.h>

#define Bb 16
#define Ll 256
#define Hh 6
#define Dm 768
#define dh 128

// ws offsets (in float slots)
#define OFF_VC   0UL
#define OFF_CO   3145728UL
#define OFF_XH   9437184UL
#define OFF_SQ   11010048UL
#define OFF_THS  11034624UL
#define OFF_PART 11059200UL
#define OFF_STAT 11060736UL
#define OFF_ACC  11060760UL

typedef __attribute__((ext_vector_type(8))) __bf16 bf16x8;
typedef __attribute__((ext_vector_type(4))) float f32x4;
typedef __attribute__((ext_vector_type(8))) unsigned short u16x8;

__device__ inline float bf2f(unsigned short u) {
  union { unsigned int i; float f; } c;
  c.i = ((unsigned int)u) << 16;
  return c.f;
}

// ---------------- K1: gather + scale -> bf16 x (B,H,L,dh), per-(bh,l) sum/sumsq ----------------
__global__ __launch_bounds__(128) void k1_gather(const int* __restrict__ tids,
    const float* __restrict__ TF, const float* __restrict__ DF,
    const float* __restrict__ emb, __hip_bfloat16* __restrict__ xh,
    float* __restrict__ sq, float* __restrict__ ths) {
  int tok = blockIdx.x;            // b*L + l
  int t = threadIdx.x;             // 0..127 = channel within head
  int tid = tids[tok];
  float w = fminf(TF[tok], 20.0f) * log1pf(1.0f / DF[tok]);
  const float* er = emb + (size_t)tid * Dm;
  int bb = tok >> 8, l = tok & 255;
  float v[6];
#pragma unroll
  for (int k = 0; k < 6; ++k) {
    float e = er[t + 128 * k] * w;
    __hip_bfloat16 hb = __float2bfloat16(e);
    float f = __bfloat162float(hb);
    xh[(((size_t)(bb * 6 + k)) * 256 + l) * 128 + t] = hb;
    v[k] = f;                       // bf16-rounded value used for ALL downstream math
  }
  __shared__ float s1[6][2], s2[6][2];
  int lane = t & 63, wid = t >> 6;
#pragma unroll
  for (int k = 0; k < 6; ++k) {
    float a = v[k], q = v[k] * v[k];
#pragma unroll
    for (int off = 32; off >= 1; off >>= 1) {
      a += __shfl_down(a, off);
      q += __shfl_down(q, off);
    }
    if (lane == 0) { s1[k][wid] = a; s2[k][wid] = q; }
  }
  __syncthreads();
  if (t < 6) {
    size_t idx = ((size_t)(bb * 6 + t)) * 256 + l;
    ths[idx] = s1[t][0] + s1[t][1];
    sq[idx]  = s2[t][0] + s2[t][1];
  }
}

// ---------------- K2: distance matrix via bf16 MFMA. Wave = 16 rows x 128 cols ----------------
__global__ __launch_bounds__(256) void k2_dist(const __hip_bfloat16* __restrict__ xh,
    const float* __restrict__ sq, float* __restrict__ co, float* __restrict__ part) {
  int bh = blockIdx.y;
  int p = blockIdx.x;              // 0..7 : rb*2 + cb
  int rb = p >> 1, cb = p & 1;
  int tid = threadIdx.x, w = tid >> 6, lane = tid & 63;
  int quad = lane >> 4, l16 = lane & 15;
  int I = rb * 64 + w * 16;
  int J = cb * 128;
  const __bf16* xb = (const __bf16*)(xh) + (size_t)bh * 256 * 128;
  // A fragments: A[m=l16][k=quad*8+j], k0*32 chunks
  bf16x8 a[4];
#pragma unroll
  for (int k0 = 0; k0 < 4; ++k0)
    a[k0] = *(const bf16x8*)(xb + (size_t)(I + l16) * 128 + k0 * 32 + quad * 8);
  const float* sqh = sq + (size_t)bh * 256;
  float si[4];
#pragma unroll
  for (int r = 0; r < 4; ++r) si[r] = sqh[I + quad * 4 + r];
  float* cob = co + (size_t)bh * 256 * 256;
  float ls1 = 0.0f, ls2 = 0.0f;
#pragma unroll
  for (int jt = 0; jt < 8; ++jt) {
    int Jc = J + jt * 16;
    f32x4 acc = {0.0f, 0.0f, 0.0f, 0.0f};
#pragma unroll
    for (int k0 = 0; k0 < 4; ++k0) {
      bf16x8 bfr = *(const bf16x8*)(xb + (size_t)(Jc + l16) * 128 + k0 * 32 + quad * 8);
      acc = __builtin_amdgcn_mfma_f32_16x16x32_bf16(a[k0], bfr, acc, 0, 0, 0);
    }
    float sj = sqh[Jc + l16];
#pragma unroll
    for (int r = 0; r < 4; ++r) {
      // C/D: row = quad*4 + r, col = l16  (m89-verified layout)
      float d2 = si[r] + sj - 2.0f * acc[r];
      float cv = sqrtf(fmaxf(d2, 1e-12f));
      cob[(size_t)(I + quad * 4 + r) * 256 + (Jc + l16)] = cv;
      ls1 += cv; ls2 += cv * cv;
    }
  }
#pragma unroll
  for (int off = 32; off >= 1; off >>= 1) {
    ls1 += __shfl_down(ls1, off);
    ls2 += __shfl_down(ls2, off);
  }
  __shared__ float rs[2][4];
  if (lane == 0) { rs[0][w] = ls1; rs[1][w] = ls2; }
  __syncthreads();
  if (tid == 0) {
    part[((size_t)bh * 8 + p) * 2 + 0] = rs[0][0] + rs[0][1] + rs[0][2] + rs[0][3];
    part[((size_t)bh * 8 + p) * 2 + 1] = rs[1][0] + rs[1][1] + rs[1][2] + rs[1][3];
  }
}

// ---------------- K3: finalize BN stats, zero logit accumulator ----------------
__global__ __launch_bounds__(384) void k3_stats(const float* __restrict__ ths,
    const float* __restrict__ sq, const float* __restrict__ part,
    float* __restrict__ stats, float* __restrict__ acc) {
  int h = threadIdx.x >> 6, lane = threadIdx.x & 63;
  float s1 = 0.0f, s2 = 0.0f;
  for (int m = 0; m < 64; ++m) {
    int f = m * 64 + lane;               // 0..4095 token id
    int bb = f >> 8, l = f & 255;
    size_t idx = ((size_t)(bb * 6 + h)) * 256 + l;
    s1 += ths[idx]; s2 += sq[idx];
  }
#pragma unroll
  for (int off = 32; off >= 1; off >>= 1) {
    s1 += __shfl_down(s1, off);
    s2 += __shfl_down(s2, off);
  }
  if (lane == 0) {
    float cnt = 524288.0f;               // B*L*dh
    float mean = s1 / cnt;
    float var = s2 / cnt - mean * mean;
    stats[h] = mean;
    stats[6 + h] = rsqrtf(var + 1e-5f);
  }
  float c1 = 0.0f, c2 = 0.0f;
#pragma unroll
  for (int t = 0; t < 2; ++t) {
    int e = lane + 64 * t;               // 0..127
    int bb = e >> 3, pp = e & 7;
    size_t pidx = ((size_t)(bb * 6 + h) * 8 + pp) * 2;
    c1 += part[pidx]; c2 += part[pidx + 1];
  }
#pragma unroll
  for (int off = 32; off >= 1; off >>= 1) {
    c1 += __shfl_down(c1, off);
    c2 += __shfl_down(c2, off);
  }
  if (lane == 0) {
    float cnt = 1048576.0f;              // B*L*L
    float mean = c1 / cnt;
    float var = c2 / cnt - mean * mean;
    stats[12 + h] = mean;
    stats[18 + h] = rsqrtf(var + 1e-5f);
  }
  if (threadIdx.x < 336) acc[threadIdx.x] = 0.0f;
}

// ---------------- K4: bn + leaky9 + mask + row softmax (wave per row) ----------------
__global__ __launch_bounds__(256) void k4_softmax(float* __restrict__ co,
    const int* __restrict__ tids, const float* __restrict__ stats) {
  int row = blockIdx.x * 4 + (threadIdx.x >> 6);   // bh*256 + i
  int lane = threadIdx.x & 63;
  int bh = row >> 8, i = row & 255;
  int b = bh / 6, h = bh % 6;
  float m = stats[12 + h], r = stats[18 + h];
  float* cr = co + (size_t)row * 256;
  float4 v = *(float4*)(cr + lane * 4);
  float t0 = (v.x - m) * r, t1 = (v.y - m) * r, t2 = (v.z - m) * r, t3 = (v.w - m) * r;
  t0 = t0 >= 0.0f ? t0 : 9.0f * t0;
  t1 = t1 >= 0.0f ? t1 : 9.0f * t1;
  t2 = t2 >= 0.0f ? t2 : 9.0f * t2;
  t3 = t3 >= 0.0f ? t3 : 9.0f * t3;
  const int* tb = tids + b * 256;
  int vi = (tb[i] != 0);
  int4 tj = *(const int4*)(tb + lane * 4);
  if (!vi || tj.x == 0) t0 = 0.0f;
  if (!vi || tj.y == 0) t1 = 0.0f;
  if (!vi || tj.z == 0) t2 = 0.0f;
  if (!vi || tj.w == 0) t3 = 0.0f;
  float mx = fmaxf(fmaxf(t0, t1), fmaxf(t2, t3));
#pragma unroll
  for (int off = 32; off >= 1; off >>= 1) mx = fmaxf(mx, __shfl_xor(mx, off));
  float e0 = expf(t0 - mx), e1 = expf(t1 - mx), e2 = expf(t2 - mx), e3 = expf(t3 - mx);
  float s = e0 + e1 + e2 + e3;
#pragma unroll
  for (int off = 32; off >= 1; off >>= 1) s += __shfl_xor(s, off);
  float inv = 1.0f / s;
  v.x = e0 * inv; v.y = e1 * inv; v.z = e2 * inv; v.w = e3 * inv;
  *(float4*)(cr + lane * 4) = v;
}

// ---------------- K5a: V_out = co_soft @ Vn (Vn from bf16 x), write Vc in (B,L,D) ----------------
__global__ __launch_bounds__(256) void k5a_vout(const float* __restrict__ co,
    const __hip_bfloat16* __restrict__ xh, const float* __restrict__ stats,
    float* __restrict__ vc) {
  int I = blockIdx.x * 64;
  int bh = blockIdx.y;
  int b = bh / 6, h = bh % 6;
  __shared__ float cs[64][68];
  __shared__ float vs[64][128];
  int tid = threadIdx.x;
  int tx = tid & 31, ty = tid >> 5;
  float vnm = stats[h], vnr = stats[6 + h];
  float4 acc[8];
#pragma unroll
  for (int s = 0; s < 8; ++s) acc[s] = make_float4(0.f, 0.f, 0.f, 0.f);
  const float* cob = co + ((size_t)bh * 256 + I) * 256;
  const __hip_bfloat16* xb = xh + (size_t)bh * 256 * 128;
  for (int Jc = 0; Jc < 256; Jc += 64) {
    {
      int c4 = (tid & 15) * 4, r0 = tid >> 4;
#pragma unroll
      for (int p = 0; p < 4; ++p) {
        int rr = r0 + 16 * p;
        *(float4*)&cs[rr][c4] = *(const float4*)(cob + (size_t)rr * 256 + Jc + c4);
      }
    }
    {
      int c8 = (tid & 15) * 8, r0 = tid >> 4;
#pragma unroll
      for (int p = 0; p < 4; ++p) {
        int j = r0 + 16 * p;
        u16x8 eu = *(const u16x8*)(xb + (size_t)(Jc + j) * 128 + c8);
        float4 f0, f1;
        f0.x = (bf2f(eu[0]) - vnm) * vnr; f0.y = (bf2f(eu[1]) - vnm) * vnr;
        f0.z = (bf2f(eu[2]) - vnm) * vnr; f0.w = (bf2f(eu[3]) - vnm) * vnr;
        f1.x = (bf2f(eu[4]) - vnm) * vnr; f1.y = (bf2f(eu[5]) - vnm) * vnr;
        f1.z = (bf2f(eu[6]) - vnm) * vnr; f1.w = (bf2f(eu[7]) - vnm) * vnr;
        *(float4*)&vs[j][c8] = f0;
        *(float4*)&vs[j][c8 + 4] = f1;
      }
    }
    __syncthreads();
#pragma unroll
    for (int j0 = 0; j0 < 64; j0 += 4) {
      float4 vn0 = *(float4*)&vs[j0 + 0][tx * 4];
      float4 vn1 = *(float4*)&vs[j0 + 1][tx * 4];
      float4 vn2 = *(float4*)&vs[j0 + 2][tx * 4];
      float4 vn3 = *(float4*)&vs[j0 + 3][tx * 4];
#pragma unroll
      for (int s = 0; s < 8; ++s) {
        float4 c4v = *(float4*)&cs[ty + 8 * s][j0];
        acc[s].x += c4v.x * vn0.x + c4v.y * vn1.x + c4v.z * vn2.x + c4v.w * vn3.x;
        acc[s].y += c4v.x * vn0.y + c4v.y * vn1.y + c4v.z * vn2.y + c4v.w * vn3.y;
        acc[s].z += c4v.x * vn0.z + c4v.y * vn1.z + c4v.z * vn2.z + c4v.w * vn3.z;
        acc[s].w += c4v.x * vn0.w + c4v.y * vn1.w + c4v.z * vn2.w + c4v.w * vn3.w;
      }
    }
    __syncthreads();
  }
  float* vcb = vc + ((size_t)b * Ll + I) * Dm + h * dh;
#pragma unroll
  for (int s = 0; s < 8; ++s)
    *(float4*)(vcb + (size_t)(ty + 8 * s) * Dm + tx * 4) = acc[s];
}

// ---------------- K5b: V_lgts = softmax(Vc@fcW^T + fcb); accumulate per (b,c) ----------------
__global__ __launch_bounds__(256) void k5b_lgts(const float* __restrict__ vc,
    const float* __restrict__ fcW, const float* __restrict__ fcb,
    float* __restrict__ acc) {
  int wid = threadIdx.x >> 6, lane = threadIdx.x & 63;
  int token = blockIdx.x * 4 + wid;
  int b = token >> 8;
  const float* vr = vc + (size_t)token * Dm;
  float part[21];
#pragma unroll
  for (int c = 0; c < 21; ++c) part[c] = 0.0f;
  for (int m = 0; m < 12; ++m) {
    float v = vr[lane + 64 * m];
#pragma unroll
    for (int c = 0; c < 21; ++c)
      part[c] += v * fcW[c * 768 + lane + 64 * m];
  }
#pragma unroll
  for (int c = 0; c < 21; ++c) {
#pragma unroll
    for (int off = 32; off >= 1; off >>= 1)
      part[c] += __shfl_down(part[c], off);
  }
  __shared__ float sp[4][21];
  if (lane == 0) {
    float mx = -1e30f;
#pragma unroll
    for (int c = 0; c < 21; ++c) { part[c] += fcb[c]; mx = fmaxf(mx, part[c]); }
    float s = 0.0f;
#pragma unroll
    for (int c = 0; c < 21; ++c) { part[c] = expf(part[c] - mx); s += part[c]; }
    float inv = 1.0f / s;
#pragma unroll
    for (int c = 0; c < 21; ++c) sp[wid][c] = part[c] * inv;
  }
  __syncthreads();
  if (threadIdx.x < 21) {
    float s = sp[0][threadIdx.x] + sp[1][threadIdx.x] + sp[2][threadIdx.x] + sp[3][threadIdx.x];
    atomicAdd(&acc[b * 21 + threadIdx.x], s);
  }
}

// ---------------- K6: final softmax over first 20 classes ----------------
__global__ __launch_bounds__(64) void k6_final(const float* __restrict__ acc,
                                               float* __restrict__ out) {
  int b = threadIdx.x;
  if (b < 16) {
    float mx = -1e30f;
    for (int c = 0; c < 20; ++c) mx = fmaxf(mx, acc[b * 21 + c]);
    float e[20], s = 0.0f;
    for (int c = 0; c < 20; ++c) { e[c] = expf(acc[b * 21 + c] - mx); s += e[c]; }
    float inv = 1.0f / s;
    for (int c = 0; c < 20; ++c) out[b * 20 + c] = e[c] * inv;
  }
}

extern "C" void kernel_launch(void* const* d_in, const int* in_sizes, int n_in,
                              void* d_out, int out_size, void* d_ws, size_t ws_size,
                              hipStream_t stream) {
  const int*   tids = (const int*)d_in[0];
  const float* TF   = (const float*)d_in[1];
  const float* DF   = (const float*)d_in[2];
  const float* emb  = (const float*)d_in[3];
  const float* fcW  = (const float*)d_in[4];
  const float* fcb  = (const float*)d_in[5];
  // d_in[6]=weiW, d_in[7]=weib: dead code (cw branch is provably all-ones)
  float* out = (float*)d_out;
  float* ws  = (float*)d_ws;
  float* vc    = ws + OFF_VC;
  float* co    = ws + OFF_CO;
  __hip_bfloat16* xh = (__hip_bfloat16*)(ws + OFF_XH);
  float* sq    = ws + OFF_SQ;
  float* ths   = ws + OFF_THS;
  float* part  = ws + OFF_PART;
  float* stats = ws + OFF_STAT;
  float* acc   = ws + OFF_ACC;

  k1_gather<<<4096, 128, 0, stream>>>(tids, TF, DF, emb, xh, sq, ths);
  k2_dist<<<dim3(8, 96), 256, 0, stream>>>(xh, sq, co, part);
  k3_stats<<<1, 384, 0, stream>>>(ths, sq, part, stats, acc);
  k4_softmax<<<6144, 256, 0, stream>>>(co, tids, stats);
  k5a_vout<<<dim3(4, 96), 256, 0, stream>>>(co, xh, stats, vc);
  k5b_lgts<<<1024, 256, 0, stream>>>(vc, fcW, fcb, acc);
  k6_final<<<1, 64, 0, stream>>>(acc, out);
}

// Round 3
// 223.522 us; speedup vs baseline: 1.9357x; 1.2358x over previous
//
#include <hip/hip_runtime.h>
#include <hip/hip_bf16.h>
#include <math.h>

#define Bb 16
#define Ll 256
#define Hh 6
#define Dm 768
#define dh 128

// ws offsets (float slots). Phase-1 tenants of the vc region (all dead before
// k5a writes vc): sq@0, ths@24576, part@49152.
#define OFF_VC   0UL
#define OFF_SQ   0UL
#define OFF_THS  24576UL
#define OFF_PART 49152UL
#define OFF_CO   3145728UL      // fp32 co (k2->k4); k4 packs bf16 in-place, row stride 512 bf16
#define OFF_XH   9437184UL      // bf16 x, (b,h,l,ch)
#define OFF_XT   11010048UL     // bf16 x^T, (b,h,ch,l)
#define OFF_STAT 12582912UL
#define OFF_ACC  12582936UL     // end: 12583272 fl = 50.33 MB

typedef __attribute__((ext_vector_type(8))) __bf16 bf16x8;
typedef __attribute__((ext_vector_type(4))) float f32x4;

// ---------------- K1: gather + scale -> bf16 x (B,H,L,dh), per-(bh,l) sum/sumsq ----------------
__global__ __launch_bounds__(128) void k1_gather(const int* __restrict__ tids,
    const float* __restrict__ TF, const float* __restrict__ DF,
    const float* __restrict__ emb, __hip_bfloat16* __restrict__ xh,
    float* __restrict__ sq, float* __restrict__ ths) {
  int tok = blockIdx.x;            // b*L + l
  int t = threadIdx.x;             // 0..127 = channel within head
  int tid = tids[tok];
  float w = fminf(TF[tok], 20.0f) * log1pf(1.0f / DF[tok]);
  const float* er = emb + (size_t)tid * Dm;
  int bb = tok >> 8, l = tok & 255;
  float v[6];
#pragma unroll
  for (int k = 0; k < 6; ++k) {
    float e = er[t + 128 * k] * w;
    __hip_bfloat16 hb = __float2bfloat16(e);
    float f = __bfloat162float(hb);
    xh[(((size_t)(bb * 6 + k)) * 256 + l) * 128 + t] = hb;
    v[k] = f;                       // bf16-rounded value used for ALL downstream math
  }
  __shared__ float s1[6][2], s2[6][2];
  int lane = t & 63, wid = t >> 6;
#pragma unroll
  for (int k = 0; k < 6; ++k) {
    float a = v[k], q = v[k] * v[k];
#pragma unroll
    for (int off = 32; off >= 1; off >>= 1) {
      a += __shfl_down(a, off);
      q += __shfl_down(q, off);
    }
    if (lane == 0) { s1[k][wid] = a; s2[k][wid] = q; }
  }
  __syncthreads();
  if (t < 6) {
    size_t idx = ((size_t)(bb * 6 + t)) * 256 + l;
    ths[idx] = s1[t][0] + s1[t][1];
    sq[idx]  = s2[t][0] + s2[t][1];
  }
}

// ---------------- K1t: xh (bh,l,ch) -> xT (bh,ch,l), LDS transpose ----------------
__global__ __launch_bounds__(256) void k1t_transpose(const __hip_bfloat16* __restrict__ xh,
    __hip_bfloat16* __restrict__ xT) {
  int tb = blockIdx.x;             // 0..3 token block
  int bh = blockIdx.y;             // 0..95
  int T0 = tb * 64;
  __shared__ __hip_bfloat16 tile[64][130];   // row 260B: 2-way max conflicts
  int tid = threadIdx.x;
  // load 64 tokens x 128 ch: thread (r=tid>>2, cg=tid&3) loads 32 ch
  {
    int r = tid >> 2, cg = tid & 3;
    const __hip_bfloat16* src = xh + ((size_t)(bh * 256 + T0 + r)) * 128 + cg * 32;
#pragma unroll
    for (int j4 = 0; j4 < 4; ++j4) {
      // 8 bf16 = 4 u32, store u32-granular to LDS (260B row stride: b32-aligned)
      const unsigned int* s32 = (const unsigned int*)(src + j4 * 8);
#pragma unroll
      for (int u = 0; u < 4; ++u)
        *(unsigned int*)&tile[r][cg * 32 + j4 * 8 + 2 * u] = s32[u];
    }
  }
  __syncthreads();
  // write out transposed: u32 = {x[2tp][c], x[2tp+1][c]}
  int tp = tid & 31, c0 = tid >> 5;
  unsigned int* xT32 = (unsigned int*)xT;
#pragma unroll
  for (int i = 0; i < 16; ++i) {
    int c = i * 8 + c0;
    unsigned int lo = *(const unsigned short*)&tile[2 * tp][c];
    unsigned int hi = *(const unsigned short*)&tile[2 * tp + 1][c];
    xT32[((size_t)(bh * 128 + c)) * 128 + T0 / 2 + tp] = lo | (hi << 16);
  }
}

// ---------------- K2: distance matrix via bf16 MFMA. Wave = 16 rows x 128 cols ----------------
__global__ __launch_bounds__(256) void k2_dist(const __hip_bfloat16* __restrict__ xh,
    const float* __restrict__ sq, float* __restrict__ co, float* __restrict__ part) {
  int bh = blockIdx.y;
  int p = blockIdx.x;              // 0..7 : rb*2 + cb
  int rb = p >> 1, cb = p & 1;
  int tid = threadIdx.x, w = tid >> 6, lane = tid & 63;
  int quad = lane >> 4, l16 = lane & 15;
  int I = rb * 64 + w * 16;
  int J = cb * 128;
  const __bf16* xb = (const __bf16*)(xh) + (size_t)bh * 256 * 128;
  bf16x8 a[4];
#pragma unroll
  for (int k0 = 0; k0 < 4; ++k0)
    a[k0] = *(const bf16x8*)(xb + (size_t)(I + l16) * 128 + k0 * 32 + quad * 8);
  const float* sqh = sq + (size_t)bh * 256;
  float si[4];
#pragma unroll
  for (int r = 0; r < 4; ++r) si[r] = sqh[I + quad * 4 + r];
  float* cob = co + (size_t)bh * 256 * 256;
  float ls1 = 0.0f, ls2 = 0.0f;
#pragma unroll
  for (int jt = 0; jt < 8; ++jt) {
    int Jc = J + jt * 16;
    f32x4 acc = {0.0f, 0.0f, 0.0f, 0.0f};
#pragma unroll
    for (int k0 = 0; k0 < 4; ++k0) {
      bf16x8 bfr = *(const bf16x8*)(xb + (size_t)(Jc + l16) * 128 + k0 * 32 + quad * 8);
      acc = __builtin_amdgcn_mfma_f32_16x16x32_bf16(a[k0], bfr, acc, 0, 0, 0);
    }
    float sj = sqh[Jc + l16];
#pragma unroll
    for (int r = 0; r < 4; ++r) {
      float d2 = si[r] + sj - 2.0f * acc[r];
      float cv = sqrtf(fmaxf(d2, 1e-12f));
      cob[(size_t)(I + quad * 4 + r) * 256 + (Jc + l16)] = cv;
      ls1 += cv; ls2 += cv * cv;
    }
  }
#pragma unroll
  for (int off = 32; off >= 1; off >>= 1) {
    ls1 += __shfl_down(ls1, off);
    ls2 += __shfl_down(ls2, off);
  }
  __shared__ float rs[2][4];
  if (lane == 0) { rs[0][w] = ls1; rs[1][w] = ls2; }
  __syncthreads();
  if (tid == 0) {
    part[((size_t)bh * 8 + p) * 2 + 0] = rs[0][0] + rs[0][1] + rs[0][2] + rs[0][3];
    part[((size_t)bh * 8 + p) * 2 + 1] = rs[1][0] + rs[1][1] + rs[1][2] + rs[1][3];
  }
}

// ---------------- K3: finalize BN stats, zero logit accumulator ----------------
__global__ __launch_bounds__(384) void k3_stats(const float* __restrict__ ths,
    const float* __restrict__ sq, const float* __restrict__ part,
    float* __restrict__ stats, float* __restrict__ acc) {
  int h = threadIdx.x >> 6, lane = threadIdx.x & 63;
  float s1 = 0.0f, s2 = 0.0f;
  for (int m = 0; m < 64; ++m) {
    int f = m * 64 + lane;               // 0..4095 token id
    int bb = f >> 8, l = f & 255;
    size_t idx = ((size_t)(bb * 6 + h)) * 256 + l;
    s1 += ths[idx]; s2 += sq[idx];
  }
#pragma unroll
  for (int off = 32; off >= 1; off >>= 1) {
    s1 += __shfl_down(s1, off);
    s2 += __shfl_down(s2, off);
  }
  if (lane == 0) {
    float cnt = 524288.0f;               // B*L*dh
    float mean = s1 / cnt;
    float var = s2 / cnt - mean * mean;
    stats[h] = mean;
    stats[6 + h] = rsqrtf(var + 1e-5f);
  }
  float c1 = 0.0f, c2 = 0.0f;
#pragma unroll
  for (int t = 0; t < 2; ++t) {
    int e = lane + 64 * t;               // 0..127
    int bb = e >> 3, pp = e & 7;
    size_t pidx = ((size_t)(bb * 6 + h) * 8 + pp) * 2;
    c1 += part[pidx]; c2 += part[pidx + 1];
  }
#pragma unroll
  for (int off = 32; off >= 1; off >>= 1) {
    c1 += __shfl_down(c1, off);
    c2 += __shfl_down(c2, off);
  }
  if (lane == 0) {
    float cnt = 1048576.0f;              // B*L*L
    float mean = c1 / cnt;
    float var = c2 / cnt - mean * mean;
    stats[12 + h] = mean;
    stats[18 + h] = rsqrtf(var + 1e-5f);
  }
  if (threadIdx.x < 336) acc[threadIdx.x] = 0.0f;
}

// ---------------- K4: bn + leaky9 + mask + row softmax; bf16 pack IN-PLACE ----------------
// Each wave owns one full fp32 row (1KB); writes bf16 result over the row's
// first 512B. Safe: no other wave touches this row.
__global__ __launch_bounds__(256) void k4_softmax(float* __restrict__ co,
    const int* __restrict__ tids, const float* __restrict__ stats) {
  int row = blockIdx.x * 4 + (threadIdx.x >> 6);   // bh*256 + i
  int lane = threadIdx.x & 63;
  int bh = row >> 8, i = row & 255;
  int b = bh / 6, h = bh % 6;
  float m = stats[12 + h], r = stats[18 + h];
  float* cr = co + (size_t)row * 256;
  float4 v = *(float4*)(cr + lane * 4);
  float t0 = (v.x - m) * r, t1 = (v.y - m) * r, t2 = (v.z - m) * r, t3 = (v.w - m) * r;
  t0 = t0 >= 0.0f ? t0 : 9.0f * t0;
  t1 = t1 >= 0.0f ? t1 : 9.0f * t1;
  t2 = t2 >= 0.0f ? t2 : 9.0f * t2;
  t3 = t3 >= 0.0f ? t3 : 9.0f * t3;
  const int* tb = tids + b * 256;
  int vi = (tb[i] != 0);
  int4 tj = *(const int4*)(tb + lane * 4);
  if (!vi || tj.x == 0) t0 = 0.0f;
  if (!vi || tj.y == 0) t1 = 0.0f;
  if (!vi || tj.z == 0) t2 = 0.0f;
  if (!vi || tj.w == 0) t3 = 0.0f;
  float mx = fmaxf(fmaxf(t0, t1), fmaxf(t2, t3));
#pragma unroll
  for (int off = 32; off >= 1; off >>= 1) mx = fmaxf(mx, __shfl_xor(mx, off));
  float e0 = expf(t0 - mx), e1 = expf(t1 - mx), e2 = expf(t2 - mx), e3 = expf(t3 - mx);
  float s = e0 + e1 + e2 + e3;
#pragma unroll
  for (int off = 32; off >= 1; off >>= 1) s += __shfl_xor(s, off);
  float inv = 1.0f / s;
  ushort4 pk;
  pk.x = __bfloat16_as_ushort(__float2bfloat16(e0 * inv));
  pk.y = __bfloat16_as_ushort(__float2bfloat16(e1 * inv));
  pk.z = __bfloat16_as_ushort(__float2bfloat16(e2 * inv));
  pk.w = __bfloat16_as_ushort(__float2bfloat16(e3 * inv));
  *(ushort4*)((__hip_bfloat16*)cr + lane * 4) = pk;
}

// ---------------- K5a: V_out = co_bf @ x via MFMA; epilogue r*(.)-r*m; vc (B,L,D) ----------------
// co rowsum == 1 exactly => co@Vn = r*(co@x) - r*m.
__global__ __launch_bounds__(256) void k5a_vout(const __hip_bfloat16* __restrict__ co_bf,
    const __hip_bfloat16* __restrict__ xT, const float* __restrict__ stats,
    float* __restrict__ vc) {
  int it = blockIdx.x;             // 0..3 row tile
  int bh = blockIdx.y;
  int b = bh / 6, h = bh % 6;
  int tid = threadIdx.x, w = tid >> 6, lane = tid & 63;
  int quad = lane >> 4, l16 = lane & 15;
  int I = it * 64 + w * 16;
  // co_bf: bf16 rows packed in-place in the fp32 co buffer -> row stride 512 bf16
  const __bf16* cb = (const __bf16*)co_bf + ((size_t)(bh * 256 + I + l16)) * 512;
  bf16x8 a[8];
#pragma unroll
  for (int k0 = 0; k0 < 8; ++k0)
    a[k0] = *(const bf16x8*)(cb + k0 * 32 + quad * 8);
  const __bf16* xb = (const __bf16*)xT + (size_t)bh * 128 * 256;
  float m = stats[h], rs = stats[6 + h];
  float rm = rs * m;
  float* vcb = vc + ((size_t)(b * 256 + I + quad * 4)) * 768 + h * 128;
#pragma unroll
  for (int jt = 0; jt < 8; ++jt) {
    int ch = jt * 16 + l16;
    const __bf16* brow = xb + (size_t)ch * 256;
    f32x4 acc = {0.0f, 0.0f, 0.0f, 0.0f};
#pragma unroll
    for (int k0 = 0; k0 < 8; ++k0) {
      bf16x8 bfr = *(const bf16x8*)(brow + k0 * 32 + quad * 8);
      acc = __builtin_amdgcn_mfma_f32_16x16x32_bf16(a[k0], bfr, acc, 0, 0, 0);
    }
#pragma unroll
    for (int r = 0; r < 4; ++r)
      vcb[(size_t)r * 768 + ch] = rs * acc[r] - rm;
  }
}

// ---------------- K5b: V_lgts = softmax(Vc@fcW^T + fcb); accumulate per (b,c) ----------------
__global__ __launch_bounds__(256) void k5b_lgts(const float* __restrict__ vc,
    const float* __restrict__ fcW, const float* __restrict__ fcb,
    float* __restrict__ acc) {
  int wid = threadIdx.x >> 6, lane = threadIdx.x & 63;
  int token = blockIdx.x * 4 + wid;
  int b = token >> 8;
  const float* vr = vc + (size_t)token * Dm;
  float part[21];
#pragma unroll
  for (int c = 0; c < 21; ++c) part[c] = 0.0f;
  for (int m = 0; m < 12; ++m) {
    float v = vr[lane + 64 * m];
#pragma unroll
    for (int c = 0; c < 21; ++c)
      part[c] += v * fcW[c * 768 + lane + 64 * m];
  }
#pragma unroll
  for (int c = 0; c < 21; ++c) {
#pragma unroll
    for (int off = 32; off >= 1; off >>= 1)
      part[c] += __shfl_down(part[c], off);
  }
  __shared__ float sp[4][21];
  if (lane == 0) {
    float mx = -1e30f;
#pragma unroll
    for (int c = 0; c < 21; ++c) { part[c] += fcb[c]; mx = fmaxf(mx, part[c]); }
    float s = 0.0f;
#pragma unroll
    for (int c = 0; c < 21; ++c) { part[c] = expf(part[c] - mx); s += part[c]; }
    float inv = 1.0f / s;
#pragma unroll
    for (int c = 0; c < 21; ++c) sp[wid][c] = part[c] * inv;
  }
  __syncthreads();
  if (threadIdx.x < 21) {
    float s = sp[0][threadIdx.x] + sp[1][threadIdx.x] + sp[2][threadIdx.x] + sp[3][threadIdx.x];
    atomicAdd(&acc[b * 21 + threadIdx.x], s);
  }
}

// ---------------- K6: final softmax over first 20 classes ----------------
__global__ __launch_bounds__(64) void k6_final(const float* __restrict__ acc,
                                               float* __restrict__ out) {
  int b = threadIdx.x;
  if (b < 16) {
    float mx = -1e30f;
    for (int c = 0; c < 20; ++c) mx = fmaxf(mx, acc[b * 21 + c]);
    float e[20], s = 0.0f;
    for (int c = 0; c < 20; ++c) { e[c] = expf(acc[b * 21 + c] - mx); s += e[c]; }
    float inv = 1.0f / s;
    for (int c = 0; c < 20; ++c) out[b * 20 + c] = e[c] * inv;
  }
}

extern "C" void kernel_launch(void* const* d_in, const int* in_sizes, int n_in,
                              void* d_out, int out_size, void* d_ws, size_t ws_size,
                              hipStream_t stream) {
  const int*   tids = (const int*)d_in[0];
  const float* TF   = (const float*)d_in[1];
  const float* DF   = (const float*)d_in[2];
  const float* emb  = (const float*)d_in[3];
  const float* fcW  = (const float*)d_in[4];
  const float* fcb  = (const float*)d_in[5];
  // d_in[6]=weiW, d_in[7]=weib: dead code (cw branch is provably all-ones)
  float* out = (float*)d_out;
  float* ws  = (float*)d_ws;
  float* vc    = ws + OFF_VC;
  float* sq    = ws + OFF_SQ;     // lives in vc region until k3
  float* ths   = ws + OFF_THS;    // lives in vc region until k3
  float* part  = ws + OFF_PART;   // lives in vc region until k3
  float* co    = ws + OFF_CO;
  __hip_bfloat16* xh = (__hip_bfloat16*)(ws + OFF_XH);
  __hip_bfloat16* xT = (__hip_bfloat16*)(ws + OFF_XT);
  float* stats = ws + OFF_STAT;
  float* acc   = ws + OFF_ACC;

  k1_gather<<<4096, 128, 0, stream>>>(tids, TF, DF, emb, xh, sq, ths);
  k1t_transpose<<<dim3(4, 96), 256, 0, stream>>>(xh, xT);
  k2_dist<<<dim3(8, 96), 256, 0, stream>>>(xh, sq, co, part);
  k3_stats<<<1, 384, 0, stream>>>(ths, sq, part, stats, acc);
  k4_softmax<<<6144, 256, 0, stream>>>(co, tids, stats);
  k5a_vout<<<dim3(4, 96), 256, 0, stream>>>((const __hip_bfloat16*)co, xT, stats, vc);
  k5b_lgts<<<1024, 256, 0, stream>>>(vc, fcW, fcb, acc);
  k6_final<<<1, 64, 0, stream>>>(acc, out);
}